// Round 2
// baseline (174.501 us; speedup 1.0000x reference)
//
#include <hip/hip_runtime.h>

// Ordered bi-bi mechanism dydt. Species: [E, EA, EQ, EAB, A, B, P, Q].
// Two lanes per element: lane pair (2j, 2j+1) holds the two float4 halves of
// element j's y-row => every global access is unit-stride float4 across the
// wave. Halves + rates exchanged via __shfl_xor(.,1).
//
// This revision: single branch-free fast path (all ITERS rows valid) with the
// structure  [8 loads] -> [all shfl/compute] -> [4 stores at end], matching
// the scheduling shape of the 6.3 TB/s copy microbenchmark. Guarded tail path
// only for the single boundary block. Normal (cached) stores — the nt hint
// was neutral-to-negative and deviates from the proven pattern.
//
// Lane-pair path safety: stride and n2 are both even, so the fast/tail
// condition (t0 + 3*stride < n2) always agrees within a lane pair => the
// __shfl_xor(.,1) partner is always active on the same path.

#define ITERS 4

__device__ __forceinline__ float4 shfl_xor1(float4 v) {
    float4 r;
    r.x = __shfl_xor(v.x, 1);
    r.y = __shfl_xor(v.y, 1);
    r.z = __shfl_xor(v.z, 1);
    r.w = __shfl_xor(v.w, 1);
    return r;
}

__device__ __forceinline__ float4 ode_compute(float4 q, float4 mine, int h) {
    // exchange y-halves with neighbor lane
    float4 p = shfl_xor1(q);
    float4 ya = h ? p : q;    // E, EA, EQ, EAB
    float4 yb = h ? q : p;    // A, B, P, Q

    // exchange rates (even lane loaded kf, odd lane loaded kr)
    float4 other = shfl_xor1(mine);
    float4 f = h ? other : mine;   // kf0..kf3
    float4 r = h ? mine : other;   // kr0..kr3

    float E  = ya.x, EA = ya.y, EQ = ya.z, EAB = ya.w;
    float A  = yb.x, Bc = yb.y, P  = yb.z, Q   = yb.w;

    float v0 = f.x * E   * A  - r.x * EA;
    float v1 = f.y * EA  * Bc - r.y * EAB;
    float v2 = f.z * EAB      - r.z * EQ * P;
    float v3 = f.w * EQ       - r.w * E  * Q;

    float4 o;
    if (h == 0) {
        o.x = v3 - v0;   // dE
        o.y = v0 - v1;   // dEA
        o.z = v2 - v3;   // dEQ
        o.w = v1 - v2;   // dEAB
    } else {
        o.x = -v0;       // dA
        o.y = -v1;       // dB
        o.z =  v2;       // dP
        o.w =  v3;       // dQ
    }
    return o;
}

__global__ __launch_bounds__(256) void ode_kernel(
    const float4* __restrict__ y4,
    const float4* __restrict__ kf4,
    const float4* __restrict__ kr4,
    float4* __restrict__ out4,
    int n2)   // n2 = 2*B (total float4 rows of y)
{
    const int stride = gridDim.x * blockDim.x;            // even
    const int t0 = blockIdx.x * blockDim.x + threadIdx.x;
    const int h = t0 & 1;

    // even lane reads forward rates, odd lane reverse rates
    const float4* __restrict__ rp = h ? kr4 : kf4;

    if (t0 + (ITERS - 1) * stride < n2) {
        // ---- fast path: branch-free. loads -> compute -> stores ----
        float4 q[ITERS], mine[ITERS];
        #pragma unroll
        for (int k = 0; k < ITERS; ++k) {
            int t = t0 + k * stride;
            q[k]    = y4[t];         // unit-stride float4 across wave
            mine[k] = rp[t >> 1];    // unit-stride float4 across lane pairs
        }

        float4 o[ITERS];
        #pragma unroll
        for (int k = 0; k < ITERS; ++k)
            o[k] = ode_compute(q[k], mine[k], h);

        #pragma unroll
        for (int k = 0; k < ITERS; ++k)
            out4[t0 + k * stride] = o[k];
    } else {
        // ---- tail path: only the boundary block lands here ----
        #pragma unroll
        for (int k = 0; k < ITERS; ++k) {
            int t = t0 + k * stride;
            if (t < n2) {
                float4 q    = y4[t];
                float4 mine = rp[t >> 1];
                out4[t] = ode_compute(q, mine, h);
            }
        }
    }
}

extern "C" void kernel_launch(void* const* d_in, const int* in_sizes, int n_in,
                              void* d_out, int out_size, void* d_ws, size_t ws_size,
                              hipStream_t stream) {
    // inputs: [0]=t (1,), [1]=y (B,8), [2]=forward_rates (B,4), [3]=reverse_rates (B,4)
    const float4* y4  = (const float4*)d_in[1];
    const float4* kf4 = (const float4*)d_in[2];
    const float4* kr4 = (const float4*)d_in[3];
    float4* out4 = (float4*)d_out;
    int B  = in_sizes[1] / 8;
    int n2 = 2 * B;

    int block = 256;
    int grid  = (n2 + block * ITERS - 1) / (block * ITERS);
    ode_kernel<<<grid, block, 0, stream>>>(y4, kf4, kr4, out4, n2);
}